// Round 6
// baseline (39.944 us; speedup 1.0000x reference)
//
#include <hip/hip_runtime.h>

// Problem constants from the reference (B=4, N=1024, D=256).
#define B_DIM 4
#define N_DIM 1024
#define D_DIM 256            // ej < 256 always (nonzero over last dim of x)
#define NROWS (B_DIM * N_DIM)
#define ITILE 8              // i-rows per block (aligned; 1024 % 8 == 0)
#define NBLK  (NROWS / ITILE)  // 512 blocks
#define LDPAD 4              // d_lds row stride 260 floats

typedef __bf16 bf16x8 __attribute__((ext_vector_type(8)));
typedef float  f32x4  __attribute__((ext_vector_type(4)));

// Single fused kernel: per-block {edge-range search || MFMA Gram tile} ->
// LDS -> coalesced edge scatter. No workspace, no second launch.
// d^2 = n_i + n_j - 2<x_i,x_j> (bf16 Gram, f32 norms), diagonal forced to 0.
__global__ __launch_bounds__(256) void fused_all_kernel(
    const float* __restrict__ x,
    const int* __restrict__ eb, const int* __restrict__ ei,
    const int* __restrict__ ej,
    float* __restrict__ out, int E)
{
    const int bid = (int)blockIdx.x;      // 0..511
    const int r0  = bid * ITILE;          // flat row key = b*1024 + i
    const int b   = r0 >> 10;
    const int i0  = r0 & (N_DIM - 1);
    const float* __restrict__ Xb = x + (size_t)b * N_DIM * D_DIM;

    __shared__ float d_lds[ITILE][D_DIM + LDPAD];
    __shared__ int s_range[2];

    const int tid = (int)threadIdx.x;

    // --- Edge-range lower_bound (threads 0,1). Keys (eb*1024+ei) are
    // nondecreasing (jnp.nonzero row-major order). Latency overlaps with this
    // block's compute phase and with the co-resident block's waves.
    if (tid < 2) {
        const int target = r0 + tid * ITILE;
        int lo = 0, hi = E;
        while (lo < hi) {
            const int mid = (lo + hi) >> 1;
            const int key = eb[mid] * N_DIM + ei[mid];
            if (key < target) lo = mid + 1; else hi = mid;
        }
        s_range[tid] = lo;
    }

    // --- MFMA Gram compute: 8 i-rows x 256 j. Wave w owns j in [64w, 64w+64).
    const int lane = tid & 63;
    const int wid  = tid >> 6;            // 0..3
    const int jbase = wid * 64;
    const int rsel = lane & 15;
    const int kg   = lane >> 4;           // k-group 0..3
    const int arow = i0 + (rsel & (ITILE - 1));   // clamp: rows 8-15 duplicate 0-7

    f32x4 acc[4] = {};
    float na = 0.f;                       // partial ||x_{arow}||^2
    float nbv[4] = {0.f, 0.f, 0.f, 0.f};

    for (int k0 = 0; k0 < D_DIM; k0 += 32) {
        bf16x8 af;
        {
            const float* rp = Xb + (size_t)arow * D_DIM + k0 + kg * 8;
            float4 v0 = *(const float4*)rp;
            float4 v1 = *(const float4*)(rp + 4);
            af[0]=(__bf16)v0.x; af[1]=(__bf16)v0.y; af[2]=(__bf16)v0.z; af[3]=(__bf16)v0.w;
            af[4]=(__bf16)v1.x; af[5]=(__bf16)v1.y; af[6]=(__bf16)v1.z; af[7]=(__bf16)v1.w;
            na += v0.x*v0.x + v0.y*v0.y + v0.z*v0.z + v0.w*v0.w
                + v1.x*v1.x + v1.y*v1.y + v1.z*v1.z + v1.w*v1.w;
        }
        bf16x8 bfrag[4];
        #pragma unroll
        for (int f = 0; f < 4; ++f) {
            const float* rp = Xb + (size_t)(jbase + f * 16 + rsel) * D_DIM + k0 + kg * 8;
            float4 v0 = *(const float4*)rp;
            float4 v1 = *(const float4*)(rp + 4);
            bfrag[f][0]=(__bf16)v0.x; bfrag[f][1]=(__bf16)v0.y; bfrag[f][2]=(__bf16)v0.z; bfrag[f][3]=(__bf16)v0.w;
            bfrag[f][4]=(__bf16)v1.x; bfrag[f][5]=(__bf16)v1.y; bfrag[f][6]=(__bf16)v1.z; bfrag[f][7]=(__bf16)v1.w;
            nbv[f] += v0.x*v0.x + v0.y*v0.y + v0.z*v0.z + v0.w*v0.w
                    + v1.x*v1.x + v1.y*v1.y + v1.z*v1.z + v1.w*v1.w;
        }
        #pragma unroll
        for (int f = 0; f < 4; ++f)
            acc[f] = __builtin_amdgcn_mfma_f32_16x16x32_bf16(af, bfrag[f], acc[f], 0, 0, 0);
    }

    // Reduce partial norms over the 4 k-groups (lanes sharing lane&15).
    na += __shfl_xor(na, 16, 64);
    na += __shfl_xor(na, 32, 64);
    #pragma unroll
    for (int f = 0; f < 4; ++f) {
        nbv[f] += __shfl_xor(nbv[f], 16, 64);
        nbv[f] += __shfl_xor(nbv[f], 32, 64);
    }

    // Epilogue: C/D layout col=lane&15, row=(lane>>4)*4+r (m89-verified).
    // Only rows rloc < ITILE are real (kg<2); banks: 32 active lanes -> 32 banks.
    #pragma unroll
    for (int f = 0; f < 4; ++f) {
        const int col = jbase + f * 16 + rsel;    // j in [0,256)
        const float nj = nbv[f];
        #pragma unroll
        for (int r = 0; r < 4; ++r) {
            const int rloc = kg * 4 + r;
            if (rloc < ITILE) {
                const float ni = __shfl(na, rloc, 64);
                float d2 = ni + nj - 2.0f * acc[f][r];
                float d  = sqrtf(fmaxf(d2, 0.0f));
                if (i0 + rloc == col) d = 0.0f;   // exact zero on diagonal
                d_lds[rloc][col] = d;
            }
        }
    }
    __syncthreads();

    // --- Scatter: this block's contiguous edge range, 32 B/edge coalesced.
    const int estart = s_range[0];
    const int eend   = s_range[1];
    for (int e = estart + tid; e < eend; e += 256) {
        const int iloc = ei[e] - i0;              // in [0, ITILE)
        const int j    = ej[e];
        const float d  = d_lds[iloc][j];
        const float4 v = make_float4(d, d, d, d);
        float* op = out + (size_t)e * 8;
        *(float4*)op       = v;
        *(float4*)(op + 4) = v;
    }
}

extern "C" void kernel_launch(void* const* d_in, const int* in_sizes, int n_in,
                              void* d_out, int out_size, void* d_ws, size_t ws_size,
                              hipStream_t stream) {
    const float* x  = (const float*)d_in[0];
    const int*   eb = (const int*)d_in[1];
    const int*   ei = (const int*)d_in[2];
    const int*   ej = (const int*)d_in[3];
    float* out = (float*)d_out;
    const int E = in_sizes[1];
    if (E <= 0) return;

    fused_all_kernel<<<NBLK, 256, 0, stream>>>(x, eb, ei, ej, out, E);
}

// Round 7
// 37.813 us; speedup vs baseline: 1.0564x; 1.0564x over previous
//
#include <hip/hip_runtime.h>

// Problem constants from the reference (B=4, N=1024, D=256).
#define B_DIM 4
#define N_DIM 1024
#define D_DIM 256             // ej < 256 always (nonzero over last dim of x)
#define NROWS (B_DIM * N_DIM) // 4096
#define ITILE 8               // i-rows per block in kernel C
#define NBLK_C (NROWS / ITILE)// 512
#define LDPAD 4               // d_lds row stride 260 floats

typedef __bf16 bf16x8 __attribute__((ext_vector_type(8)));
typedef __bf16 bf16x4 __attribute__((ext_vector_type(4)));
typedef float  f32x4  __attribute__((ext_vector_type(4)));

// ---- Kernel A: bf16 copy of x + exact f32 row norms -----------------------
// One wave per row: 64 lanes x 4 floats = 256 = D.
__global__ __launch_bounds__(256) void prep_kernel(
    const float* __restrict__ x, __bf16* __restrict__ xb16,
    float* __restrict__ norms)
{
    const int wid  = (int)(threadIdx.x >> 6);
    const int lane = (int)(threadIdx.x & 63u);
    const int row  = (int)blockIdx.x * 4 + wid;      // 0..4095
    const float4 v = *(const float4*)(x + (size_t)row * D_DIM + lane * 4);
    bf16x4 h;
    h[0] = (__bf16)v.x; h[1] = (__bf16)v.y; h[2] = (__bf16)v.z; h[3] = (__bf16)v.w;
    *(bf16x4*)(xb16 + (size_t)row * D_DIM + lane * 4) = h;
    float s = v.x*v.x + v.y*v.y + v.z*v.z + v.w*v.w;
    #pragma unroll
    for (int off = 32; off >= 1; off >>= 1) s += __shfl_xor(s, off, 64);
    if (lane == 0) norms[row] = s;
}

// ---- Kernel B: row_start via boundary scatter (coalesced, chain-free) -----
// Keys (eb*1024+ei) nondecreasing (jnp.nonzero row-major order).
__global__ __launch_bounds__(256) void row_bounds_kernel(
    const int* __restrict__ eb, const int* __restrict__ ei,
    int* __restrict__ row_start, int E)
{
    const int e = (int)blockIdx.x * 256 + (int)threadIdx.x;
    if (e >= E) return;
    const int key  = eb[e] * N_DIM + ei[e];
    const int prev = (e == 0) ? -1 : (eb[e - 1] * N_DIM + ei[e - 1]);
    for (int r = prev + 1; r <= key; ++r) row_start[r] = e;
    if (e == E - 1)
        for (int r = key + 1; r <= NROWS; ++r) row_start[r] = E;
}

// ---- Kernel C: MFMA Gram tile from bf16 + table norms + edge scatter ------
// 512 blocks x 512 threads (8 waves -> 16 waves/CU). Block owns 8 i-rows x
// 256 j; wave w owns j in [32w, 32w+32) via 2 fragments. K-loop per iter:
// 3 bf16x8 loads + 2 MFMA — no converts, no norm FMAs (chain-minimal).
__global__ __launch_bounds__(512) void gram_scatter_kernel(
    const __bf16* __restrict__ xb16, const float* __restrict__ norms,
    const int* __restrict__ ei, const int* __restrict__ ej,
    const int* __restrict__ row_start, float* __restrict__ out)
{
    const int bid = (int)blockIdx.x;     // 0..511
    const int r0  = bid * ITILE;         // flat row = b*1024 + i
    const int b   = r0 >> 10;
    const int i0  = r0 & (N_DIM - 1);
    const __bf16* __restrict__ Xh = xb16 + (size_t)b * N_DIM * D_DIM;

    __shared__ float d_lds[ITILE][D_DIM + LDPAD];

    const int tid  = (int)threadIdx.x;
    const int lane = tid & 63;
    const int wid  = tid >> 6;           // 0..7
    const int jbase = wid * 32;
    const int rsel = lane & 15;
    const int kg   = lane >> 4;          // k-group 0..3

    // Issue range loads now; consumed after the sync (latency hidden by k-loop).
    const int estart = row_start[r0];
    const int eend   = row_start[r0 + ITILE];

    const __bf16* arp  = Xh + (size_t)(i0 + (rsel & (ITILE - 1))) * D_DIM + kg * 8;
    const __bf16* brp0 = Xh + (size_t)(jbase + rsel) * D_DIM + kg * 8;
    const __bf16* brp1 = Xh + (size_t)(jbase + 16 + rsel) * D_DIM + kg * 8;

    f32x4 acc[2] = {};
    #pragma unroll
    for (int k0 = 0; k0 < D_DIM; k0 += 32) {
        const bf16x8 af = *(const bf16x8*)(arp + k0);
        const bf16x8 b0 = *(const bf16x8*)(brp0 + k0);
        const bf16x8 b1 = *(const bf16x8*)(brp1 + k0);
        acc[0] = __builtin_amdgcn_mfma_f32_16x16x32_bf16(af, b0, acc[0], 0, 0, 0);
        acc[1] = __builtin_amdgcn_mfma_f32_16x16x32_bf16(af, b1, acc[1], 0, 0, 0);
    }

    // Epilogue: C/D layout col=lane&15, row=(lane>>4)*4+r (m89-verified).
    // Rows >= ITILE are duplicates (kg >= 2 idle here).
    #pragma unroll
    for (int f = 0; f < 2; ++f) {
        const int col = jbase + f * 16 + rsel;     // j in [0,256)
        const float nj = norms[b * N_DIM + col];
        #pragma unroll
        for (int r = 0; r < 4; ++r) {
            const int rloc = kg * 4 + r;
            if (rloc < ITILE) {
                const float ni = norms[b * N_DIM + i0 + rloc];
                float d2 = ni + nj - 2.0f * acc[f][r];
                float d  = sqrtf(fmaxf(d2, 0.0f));
                if (i0 + rloc == col) d = 0.0f;    // exact zero on diagonal
                d_lds[rloc][col] = d;
            }
        }
    }
    __syncthreads();

    // Scatter: contiguous edge range, 32 B/edge, coalesced.
    for (int e = estart + tid; e < eend; e += 512) {
        const int iloc = ei[e] - i0;               // in [0, ITILE)
        const int j    = ej[e];
        const float d  = d_lds[iloc][j];
        const float4 v = make_float4(d, d, d, d);
        float* op = out + (size_t)e * 8;
        *(float4*)op       = v;
        *(float4*)(op + 4) = v;
    }
}

// ---- Fallback (ws too small): direct per-edge wave ------------------------
__global__ __launch_bounds__(256) void edge_dist_direct_kernel(
    const float* __restrict__ x,
    const int* __restrict__ eb, const int* __restrict__ ei,
    const int* __restrict__ ej, float* __restrict__ out, int E)
{
    const int wave = (int)((blockIdx.x * (unsigned)blockDim.x + threadIdx.x) >> 6);
    if (wave >= E) return;
    const int lane = (int)(threadIdx.x & 63u);
    const int b = eb[wave], i = ei[wave], j = ej[wave];
    const float4 a = reinterpret_cast<const float4*>(x + ((size_t)b * N_DIM + i) * D_DIM)[lane];
    const float4 c = reinterpret_cast<const float4*>(x + ((size_t)b * N_DIM + j) * D_DIM)[lane];
    const float dx = a.x - c.x, dy = a.y - c.y, dz = a.z - c.z, dw = a.w - c.w;
    float s = dx * dx + dy * dy + dz * dz + dw * dw;
    #pragma unroll
    for (int off = 32; off >= 1; off >>= 1) s += __shfl_xor(s, off, 64);
    const float d = sqrtf(s);
    if (lane < 2)
        reinterpret_cast<float4*>(out + (size_t)wave * 8)[lane] =
            make_float4(d, d, d, d);
}

extern "C" void kernel_launch(void* const* d_in, const int* in_sizes, int n_in,
                              void* d_out, int out_size, void* d_ws, size_t ws_size,
                              hipStream_t stream) {
    const float* x  = (const float*)d_in[0];
    const int*   eb = (const int*)d_in[1];
    const int*   ei = (const int*)d_in[2];
    const int*   ej = (const int*)d_in[3];
    float* out = (float*)d_out;
    const int E = in_sizes[1];
    if (E <= 0) return;

    // ws layout: xb16 (2 MB) | norms (16 KB) | row_start (16.4 KB)
    const size_t xb16_bytes  = (size_t)NROWS * D_DIM * sizeof(__bf16); // 2 MB
    const size_t norms_bytes = (size_t)NROWS * sizeof(float);          // 16 KB
    const size_t rs_bytes    = (size_t)(NROWS + 1) * sizeof(int);
    const size_t need = xb16_bytes + norms_bytes + rs_bytes;

    if (ws_size >= need) {
        __bf16* xb16     = (__bf16*)d_ws;
        float*  norms    = (float*)((char*)d_ws + xb16_bytes);
        int*    row_start = (int*)((char*)d_ws + xb16_bytes + norms_bytes);
        prep_kernel<<<NROWS / 4, 256, 0, stream>>>(x, xb16, norms);
        row_bounds_kernel<<<(E + 255) / 256, 256, 0, stream>>>(eb, ei, row_start, E);
        gram_scatter_kernel<<<NBLK_C, 512, 0, stream>>>(xb16, norms, ei, ej, row_start, out);
    } else {
        const int blocks = (E + 3) / 4;  // 4 waves/block
        edge_dist_direct_kernel<<<blocks, 256, 0, stream>>>(x, eb, ei, ej, out, E);
    }
}

// Round 8
// 30.770 us; speedup vs baseline: 1.2982x; 1.2289x over previous
//
#include <hip/hip_runtime.h>

// Problem constants from the reference (B=4, N=1024, D=256).
#define B_DIM 4
#define N_DIM 1024
#define D_DIM 256             // ej < 256 always (nonzero over last dim of x)
#define NROWS (B_DIM * N_DIM) // 4096
#define ITILE 8               // i-rows per block in gram kernel
#define NBLK_G (NROWS / ITILE)// 512

typedef __bf16 bf16x8 __attribute__((ext_vector_type(8)));
typedef __bf16 bf16x4 __attribute__((ext_vector_type(4)));
typedef float  f32x4  __attribute__((ext_vector_type(4)));

// ---- Kernel A: bf16 copy of x + exact f32 row norms -----------------------
// One wave per row: 64 lanes x 4 floats = 256 = D. Full occupancy.
__global__ __launch_bounds__(256) void prep_kernel(
    const float* __restrict__ x, __bf16* __restrict__ xb16,
    float* __restrict__ norms)
{
    const int wid  = (int)(threadIdx.x >> 6);
    const int lane = (int)(threadIdx.x & 63u);
    const int row  = (int)blockIdx.x * 4 + wid;      // 0..4095
    const float4 v = *(const float4*)(x + (size_t)row * D_DIM + lane * 4);
    bf16x4 h;
    h[0] = (__bf16)v.x; h[1] = (__bf16)v.y; h[2] = (__bf16)v.z; h[3] = (__bf16)v.w;
    *(bf16x4*)(xb16 + (size_t)row * D_DIM + lane * 4) = h;
    float s = v.x*v.x + v.y*v.y + v.z*v.z + v.w*v.w;
    #pragma unroll
    for (int off = 32; off >= 1; off >>= 1) s += __shfl_xor(s, off, 64);
    if (lane == 0) norms[row] = s;
}

// ---- Kernel B: MFMA Gram tile -> Dtab[b][i][j] = ||x_i - x_j|| ------------
// 512 blocks x 512 threads (8 waves). Block owns 8 i-rows x 256 j; wave w
// owns j in [32w, 32w+32) via 2 fragments. K-loop: 3 bf16x8 loads + 2 MFMA.
// Epilogue: d = sqrt(max(n_i + n_j - 2G, 0)), diag = 0, direct global store.
__global__ __launch_bounds__(512) void gram_dtab_kernel(
    const __bf16* __restrict__ xb16, const float* __restrict__ norms,
    float* __restrict__ Dtab)
{
    const int bid = (int)blockIdx.x;     // 0..511
    const int r0  = bid * ITILE;         // flat row = b*1024 + i
    const int b   = r0 >> 10;
    const int i0  = r0 & (N_DIM - 1);
    const __bf16* __restrict__ Xh = xb16 + (size_t)b * N_DIM * D_DIM;

    const int tid  = (int)threadIdx.x;
    const int lane = tid & 63;
    const int wid  = tid >> 6;           // 0..7
    const int jbase = wid * 32;
    const int rsel = lane & 15;
    const int kg   = lane >> 4;          // k-group 0..3

    const __bf16* arp  = Xh + (size_t)(i0 + (rsel & (ITILE - 1))) * D_DIM + kg * 8;
    const __bf16* brp0 = Xh + (size_t)(jbase + rsel) * D_DIM + kg * 8;
    const __bf16* brp1 = Xh + (size_t)(jbase + 16 + rsel) * D_DIM + kg * 8;

    f32x4 acc[2] = {};
    #pragma unroll
    for (int k0 = 0; k0 < D_DIM; k0 += 32) {
        const bf16x8 af = *(const bf16x8*)(arp + k0);
        const bf16x8 b0 = *(const bf16x8*)(brp0 + k0);
        const bf16x8 b1 = *(const bf16x8*)(brp1 + k0);
        acc[0] = __builtin_amdgcn_mfma_f32_16x16x32_bf16(af, b0, acc[0], 0, 0, 0);
        acc[1] = __builtin_amdgcn_mfma_f32_16x16x32_bf16(af, b1, acc[1], 0, 0, 0);
    }

    // Epilogue: C/D layout col=lane&15, row=(lane>>4)*4+r (m89-verified).
    // Rows >= ITILE are duplicates of rows 0..7 (kg >= 2 stores nothing).
    #pragma unroll
    for (int f = 0; f < 2; ++f) {
        const int col = jbase + f * 16 + rsel;     // j in [0,256)
        const float nj = norms[b * N_DIM + col];
        #pragma unroll
        for (int r = 0; r < 4; ++r) {
            const int rloc = kg * 4 + r;
            if (rloc < ITILE) {
                const float ni = norms[r0 + rloc];
                float d2 = ni + nj - 2.0f * acc[f][r];
                float d  = sqrtf(fmaxf(d2, 0.0f));
                if (i0 + rloc == col) d = 0.0f;    // exact zero on diagonal
                Dtab[((size_t)(r0 + rloc)) * D_DIM + col] = d;
            }
        }
    }
}

// ---- Kernel C: edge gather, full occupancy --------------------------------
// 2 threads per edge; each writes one float4 (16 B, coalesced). Dtab is
// L3-resident (4 MB); consecutive edges share cache lines (j nearly dense).
__global__ __launch_bounds__(256) void edge_out_kernel(
    const int* __restrict__ eb, const int* __restrict__ ei,
    const int* __restrict__ ej, const float* __restrict__ Dtab,
    float* __restrict__ out, int E)
{
    const int t = (int)blockIdx.x * 256 + (int)threadIdx.x;
    const int e = t >> 1;
    if (e >= E) return;
    const float d = Dtab[((size_t)eb[e] * N_DIM + ei[e]) * D_DIM + ej[e]];
    *(float4*)(out + (size_t)e * 8 + (t & 1) * 4) = make_float4(d, d, d, d);
}

// ---- Fallback (ws too small): direct per-edge wave ------------------------
__global__ __launch_bounds__(256) void edge_dist_direct_kernel(
    const float* __restrict__ x,
    const int* __restrict__ eb, const int* __restrict__ ei,
    const int* __restrict__ ej, float* __restrict__ out, int E)
{
    const int wave = (int)((blockIdx.x * (unsigned)blockDim.x + threadIdx.x) >> 6);
    if (wave >= E) return;
    const int lane = (int)(threadIdx.x & 63u);
    const int b = eb[wave], i = ei[wave], j = ej[wave];
    const float4 a = reinterpret_cast<const float4*>(x + ((size_t)b * N_DIM + i) * D_DIM)[lane];
    const float4 c = reinterpret_cast<const float4*>(x + ((size_t)b * N_DIM + j) * D_DIM)[lane];
    const float dx = a.x - c.x, dy = a.y - c.y, dz = a.z - c.z, dw = a.w - c.w;
    float s = dx * dx + dy * dy + dz * dz + dw * dw;
    #pragma unroll
    for (int off = 32; off >= 1; off >>= 1) s += __shfl_xor(s, off, 64);
    const float d = sqrtf(s);
    if (lane < 2)
        reinterpret_cast<float4*>(out + (size_t)wave * 8)[lane] =
            make_float4(d, d, d, d);
}

extern "C" void kernel_launch(void* const* d_in, const int* in_sizes, int n_in,
                              void* d_out, int out_size, void* d_ws, size_t ws_size,
                              hipStream_t stream) {
    const float* x  = (const float*)d_in[0];
    const int*   eb = (const int*)d_in[1];
    const int*   ei = (const int*)d_in[2];
    const int*   ej = (const int*)d_in[3];
    float* out = (float*)d_out;
    const int E = in_sizes[1];
    if (E <= 0) return;

    // ws layout: xb16 (2 MB) | norms (16 KB) | Dtab (4 MB)
    const size_t xb16_bytes  = (size_t)NROWS * D_DIM * sizeof(__bf16);
    const size_t norms_bytes = (size_t)NROWS * sizeof(float);
    const size_t dtab_bytes  = (size_t)NROWS * D_DIM * sizeof(float);
    const size_t need = xb16_bytes + norms_bytes + dtab_bytes;

    if (ws_size >= need) {
        __bf16* xb16  = (__bf16*)d_ws;
        float*  norms = (float*)((char*)d_ws + xb16_bytes);
        float*  Dtab  = (float*)((char*)d_ws + xb16_bytes + norms_bytes);
        prep_kernel<<<NROWS / 4, 256, 0, stream>>>(x, xb16, norms);
        gram_dtab_kernel<<<NBLK_G, 512, 0, stream>>>(xb16, norms, Dtab);
        const int threads = 2 * E;
        edge_out_kernel<<<(threads + 255) / 256, 256, 0, stream>>>(eb, ei, ej, Dtab, out, E);
    } else {
        const int blocks = (E + 3) / 4;  // 4 waves/block
        edge_dist_direct_kernel<<<blocks, 256, 0, stream>>>(x, eb, ei, ej, out, E);
    }
}